// Round 24
// baseline (76.017 us; speedup 1.0000x reference)
//
#include <hip/hip_runtime.h>

#define BB   8
#define NBL  2000
#define RR   10000
#define XDIM 2000

// v += dpp_permuted(v): single VALU op (v_add_f32 with DPP modifier), no DS pipe.
// Full 64-lane sum sequence (standard GCN DPP reduction; result in lane 63).
template <int CTRL>
__device__ __forceinline__ float dpp_add(float v) {
    int s = __builtin_amdgcn_update_dpp(0, __float_as_int(v), CTRL, 0xf, 0xf, true);
    return v + __int_as_float(s);
}

// ---------------- kernel A (champion, byte-identical to R23): mem2[q][b][nb]
__global__ __launch_bounds__(256, 4) void kA_gemm(
    const float* __restrict__ in1, const float* __restrict__ in2,
    const float* __restrict__ in3, const float* __restrict__ in4,
    const float* __restrict__ in5,
    const float* __restrict__ Wfc, const float* __restrict__ bfc,
    const float* __restrict__ bfv, float* __restrict__ mem2,
    unsigned* __restrict__ counter)
{
    // re-arm the kernel-B barrier every call (stream order publishes it before kB)
    if (blockIdx.x == 0 && threadIdx.x == 0) *counter = 0u;

    const int tid  = threadIdx.x;
    const int wave = tid >> 6, lane = tid & 63;     // wave = column quarter 0..3
    const int nb    = blockIdx.x;                   // 0..1999
    const int rbase = nb * 5;

    float acc[5][BB];
    #pragma unroll
    for (int q = 0; q < 5; ++q)
        #pragma unroll
        for (int b = 0; b < BB; ++b) acc[q][b] = 0.f;

    #pragma unroll
    for (int i = 0; i < 2; ++i) {
        const int col = wave * 512 + i * 256 + (lane << 2);   // float4-aligned
        const bool valid = col < XDIM;              // tail: wave==3,i==1, lanes>=52
        const int wh  = col / 400;                  // concat segment (5 only if invalid)
        const int off = col - wh * 400;             // f4 never crosses a 400-boundary
        const float* xp = in1;
        xp = (wh == 1) ? in2 : xp;
        xp = (wh == 2) ? in3 : xp;
        xp = (wh == 3) ? in4 : xp;
        xp = (wh == 4) ? in5 : xp;

        float4 w[5];
        #pragma unroll
        for (int q = 0; q < 5; ++q)
            w[q] = valid ? *(const float4*)(Wfc + (size_t)(rbase + q) * XDIM + col)
                         : make_float4(0.f, 0.f, 0.f, 0.f);

        #pragma unroll
        for (int b = 0; b < BB; ++b) {
            float4 xv = valid ? *(const float4*)(xp + b * 400 + off)
                              : make_float4(0.f, 0.f, 0.f, 0.f);
            #pragma unroll
            for (int q = 0; q < 5; ++q)
                acc[q][b] += w[q].x * xv.x + w[q].y * xv.y + w[q].z * xv.z + w[q].w * xv.w;
        }
    }

    // intra-wave reduce: 6 DPP adds, all VALU pipe; total lands in lane 63
    __shared__ float part[4][5][BB];                // [wave][q][b], 640 B
    #pragma unroll
    for (int q = 0; q < 5; ++q) {
        #pragma unroll
        for (int b = 0; b < BB; ++b) {
            float v = acc[q][b];
            v = dpp_add<0xB1>(v);                   // quad xor1
            v = dpp_add<0x4E>(v);                   // quad xor2
            v = dpp_add<0x141>(v);                  // row_half_mirror
            v = dpp_add<0x140>(v);                  // row_mirror -> row sums
            v = dpp_add<0x142>(v);                  // row_bcast15
            v = dpp_add<0x143>(v);                  // row_bcast31 -> lane 63 total
            if (lane == 63) part[wave][q][b] = v;
        }
    }
    __syncthreads();

    if (wave == 0 && lane < 40) {                   // 40 outputs: q = lane>>3, b = lane&7
        const int q = lane >> 3, b = lane & 7;
        const int r = rbase + q;
        const float v = part[0][q][b] + part[1][q][b] + part[2][q][b] + part[3][q][b];
        mem2[(q * BB + b) * NBL + nb] = v + bfc[r] + bfv[r] + 0.05f;
    }
}

// ---------------- kernel B (champion, byte-identical): select+spike -> barrier ->
// GEMV with W_mlp LDS-staged by non-select waves during the spin window.
// IDEMPOTENT: re-run reads unchanged mem2, writes identical spike/out values;
// counter>=40 on the second run just releases the barrier immediately.
__device__ __forceinline__ unsigned sortkey(float f) {
    unsigned u = __float_as_uint(f);
    return (u & 0x80000000u) ? ~u : (u | 0x80000000u);
}
__device__ __forceinline__ float unsortkey(unsigned u) {
    unsigned ub = (u & 0x80000000u) ? (u ^ 0x80000000u) : ~u;
    return __uint_as_float(ub);
}

__global__ __launch_bounds__(512) void kB_spike_out(
    const float* __restrict__ mem2, const float* __restrict__ Wmlp,
    const float* __restrict__ bmlp, float* __restrict__ spike_out,
    float* __restrict__ out, unsigned* __restrict__ counter)
{
    __shared__ float wlds[RR];                       // 40 KB: W_mlp row o
    const int tid = threadIdx.x;
    const int blk = blockIdx.x;                      // 100 blocks
    const bool is_sel = (blk < 40) && (tid < 64);    // select wave

    // ---- stage W_mlp[o] into LDS (all non-select threads; overlaps select below)
    if (!is_sel) {
        const int nstage = (blk < 40) ? 448 : 512;
        const int stid   = (blk < 40) ? (tid - 64) : tid;
        for (int j = stid; j < 2500; j += nstage) {
            const int col = j * 4;
            *(float4*)&wlds[col] = *(const float4*)(Wmlp + (size_t)blk * RR + col);
        }
    }

    // ---- phase A: blocks 0..39, wave 0 only — exact order stats + spike write
    if (is_sel) {
        const int b = blk / 5, k = blk - b * 5;
        const int lane = tid;
        const float* src = mem2 + (k * BB + b) * NBL;

        float    f[32];
        unsigned u[32];
        #pragma unroll
        for (int i = 0; i < 32; ++i) {
            int nb = i * 64 + lane;
            f[i] = (nb < NBL) ? src[nb] : 0.f;
            u[i] = (nb < NBL) ? sortkey(f[i]) : 0u;  // pad key = smallest
        }

        // rank-159 (160th largest): max X with count(u >= X) >= 160 (ballot+popc)
        unsigned X = 0;
        for (int bit = 31; bit >= 0; --bit) {
            unsigned cand = X | (1u << bit);
            int c = 0;
            #pragma unroll
            for (int i = 0; i < 32; ++i)
                c += (int)__popcll(__ballot(u[i] >= cand));
            if (c >= 160) X = cand;
        }
        const unsigned q2u = X;                      // mem_q2 (rank 159)

        int cge = 0;
        #pragma unroll
        for (int i = 0; i < 32; ++i)
            cge += (int)__popcll(__ballot(u[i] >= q2u));

        unsigned q1u;
        if (cge >= 161) {
            q1u = q2u;                               // ties reach rank 160
        } else {
            unsigned m = 0;
            #pragma unroll
            for (int i = 0; i < 32; ++i)
                if (u[i] < q2u && u[i] > m) m = u[i];
            #pragma unroll
            for (int o = 32; o >= 1; o >>= 1) {
                unsigned ot = __shfl_xor(m, o, 64);
                m = (ot > m) ? ot : m;
            }
            q1u = m;                                 // mem_q1 (rank 160)
        }

        const float q2 = unsortkey(q2u), q1 = unsortkey(q1u);
        const float nps = q1 + (q2 - q1) * 0.2f;

        #pragma unroll
        for (int i = 0; i < 32; ++i) {
            int nb = i * 64 + lane;
            if (nb < NBL)
                spike_out[b * RR + nb * 5 + k] = (f[i] - nps > 0.1f) ? 1.0f : 0.0f;
        }
        __threadfence();                             // release spike stores
        if (lane == 0) atomicAdd(counter, 1u);       // device-scope by default
    }

    // ---- barrier: all 100 blocks co-resident (<=256 CUs), spin on counter
    __syncthreads();                                 // also fences the LDS staging
    if (tid == 0) {
        while (__hip_atomic_load(counter, __ATOMIC_ACQUIRE, __HIP_MEMORY_SCOPE_AGENT) < 40u)
            __builtin_amdgcn_s_sleep(2);
        __threadfence();                             // belt-and-braces acquire
    }
    __syncthreads();

    // ---- phase B: block = output column o; out[b][o] = spike[b]·W_mlp[o] + b_mlp[o]
    const int o = blk;
    const int wave = tid >> 6, lane = tid & 63;

    float acc[BB];
    #pragma unroll
    for (int b = 0; b < BB; ++b) acc[b] = 0.f;

    #pragma unroll
    for (int i = 0; i < 5; ++i) {
        int col = i * 2048 + tid * 4;                // 512 thr × f4 = 2048 floats/iter
        if (col < RR) {                              // last valid f4 at 9996
            float4 w = *(const float4*)&wlds[col];
            #pragma unroll
            for (int b = 0; b < BB; ++b) {
                float4 s = *(const float4*)(spike_out + b * RR + col);
                acc[b] += w.x * s.x + w.y * s.y + w.z * s.z + w.w * s.w;
            }
        }
    }

    __shared__ float red[8][BB];
    #pragma unroll
    for (int b = 0; b < BB; ++b) {
        float v = acc[b];
        #pragma unroll
        for (int off = 32; off >= 1; off >>= 1) v += __shfl_xor(v, off, 64);
        if (lane == 0) red[wave][b] = v;
    }
    __syncthreads();
    if (tid < BB) {
        float v = 0.f;
        #pragma unroll
        for (int w = 0; w < 8; ++w) v += red[w][tid];
        out[tid * 100 + o] = v + bmlp[o];
    }
}

extern "C" void kernel_launch(void* const* d_in, const int* in_sizes, int n_in,
                              void* d_out, int out_size, void* d_ws, size_t ws_size,
                              hipStream_t stream) {
    const float* in1  = (const float*)d_in[0];
    const float* in2  = (const float*)d_in[1];
    const float* in3  = (const float*)d_in[2];
    const float* in4  = (const float*)d_in[3];
    const float* in5  = (const float*)d_in[4];
    const float* Wfc  = (const float*)d_in[5];
    const float* bfc  = (const float*)d_in[6];
    // d_in[7] = W_fv : multiplied by zero spikes — never read (saves 400 MB)
    const float* bfv  = (const float*)d_in[8];
    const float* Wmlp = (const float*)d_in[9];
    const float* bmlp = (const float*)d_in[10];

    float* out   = (float*)d_out;          // 8*100 = 800 floats
    float* spike = out + 800;              // 8*10000 floats (r_sumspike)

    float*    mem2    = (float*)d_ws;      // 80000 floats, layout [q][b][nb]
    unsigned* counter = (unsigned*)((char*)d_ws + 80000 * sizeof(float));

    kA_gemm<<<2000, 256, 0, stream>>>(in1, in2, in3, in4, in5, Wfc, bfc, bfv,
                                      mem2, counter);
    // DIAGNOSTIC: kB twice (idempotent). dur - 50.9 = marginal (warm) kB cost.
    kB_spike_out<<<100, 512, 0, stream>>>(mem2, Wmlp, bmlp, spike, out, counter);
    kB_spike_out<<<100, 512, 0, stream>>>(mem2, Wmlp, bmlp, spike, out, counter);
}

// Round 25
// 57.683 us; speedup vs baseline: 1.3179x; 1.3179x over previous
//
#include <hip/hip_runtime.h>

#define BB   8
#define NBL  2000
#define RR   10000
#define XDIM 2000

// v += dpp_permuted(v): single VALU op (v_add_f32 with DPP modifier), no DS pipe.
// Full 64-lane sum sequence (standard GCN DPP reduction; result in lane 63).
template <int CTRL>
__device__ __forceinline__ float dpp_add(float v) {
    int s = __builtin_amdgcn_update_dpp(0, __float_as_int(v), CTRL, 0xf, 0xf, true);
    return v + __int_as_float(s);
}

// ---------------- kernel A (champion, byte-identical to R23): mem2[q][b][nb]
__global__ __launch_bounds__(256, 4) void kA_gemm(
    const float* __restrict__ in1, const float* __restrict__ in2,
    const float* __restrict__ in3, const float* __restrict__ in4,
    const float* __restrict__ in5,
    const float* __restrict__ Wfc, const float* __restrict__ bfc,
    const float* __restrict__ bfv, float* __restrict__ mem2,
    unsigned* __restrict__ counter)
{
    // re-arm the kernel-B barrier every call (stream order publishes it before kB)
    if (blockIdx.x == 0 && threadIdx.x == 0) *counter = 0u;

    const int tid  = threadIdx.x;
    const int wave = tid >> 6, lane = tid & 63;     // wave = column quarter 0..3
    const int nb    = blockIdx.x;                   // 0..1999
    const int rbase = nb * 5;

    float acc[5][BB];
    #pragma unroll
    for (int q = 0; q < 5; ++q)
        #pragma unroll
        for (int b = 0; b < BB; ++b) acc[q][b] = 0.f;

    #pragma unroll
    for (int i = 0; i < 2; ++i) {
        const int col = wave * 512 + i * 256 + (lane << 2);   // float4-aligned
        const bool valid = col < XDIM;              // tail: wave==3,i==1, lanes>=52
        const int wh  = col / 400;                  // concat segment (5 only if invalid)
        const int off = col - wh * 400;             // f4 never crosses a 400-boundary
        const float* xp = in1;
        xp = (wh == 1) ? in2 : xp;
        xp = (wh == 2) ? in3 : xp;
        xp = (wh == 3) ? in4 : xp;
        xp = (wh == 4) ? in5 : xp;

        float4 w[5];
        #pragma unroll
        for (int q = 0; q < 5; ++q)
            w[q] = valid ? *(const float4*)(Wfc + (size_t)(rbase + q) * XDIM + col)
                         : make_float4(0.f, 0.f, 0.f, 0.f);

        #pragma unroll
        for (int b = 0; b < BB; ++b) {
            float4 xv = valid ? *(const float4*)(xp + b * 400 + off)
                              : make_float4(0.f, 0.f, 0.f, 0.f);
            #pragma unroll
            for (int q = 0; q < 5; ++q)
                acc[q][b] += w[q].x * xv.x + w[q].y * xv.y + w[q].z * xv.z + w[q].w * xv.w;
        }
    }

    // intra-wave reduce: 6 DPP adds, all VALU pipe; total lands in lane 63
    __shared__ float part[4][5][BB];                // [wave][q][b], 640 B
    #pragma unroll
    for (int q = 0; q < 5; ++q) {
        #pragma unroll
        for (int b = 0; b < BB; ++b) {
            float v = acc[q][b];
            v = dpp_add<0xB1>(v);                   // quad xor1
            v = dpp_add<0x4E>(v);                   // quad xor2
            v = dpp_add<0x141>(v);                  // row_half_mirror
            v = dpp_add<0x140>(v);                  // row_mirror -> row sums
            v = dpp_add<0x142>(v);                  // row_bcast15
            v = dpp_add<0x143>(v);                  // row_bcast31 -> lane 63 total
            if (lane == 63) part[wave][q][b] = v;
        }
    }
    __syncthreads();

    if (wave == 0 && lane < 40) {                   // 40 outputs: q = lane>>3, b = lane&7
        const int q = lane >> 3, b = lane & 7;
        const int r = rbase + q;
        const float v = part[0][q][b] + part[1][q][b] + part[2][q][b] + part[3][q][b];
        mem2[(q * BB + b) * NBL + nb] = v + bfc[r] + bfv[r] + 0.05f;
    }
}

// ---------------- kernel B: select+spike(+bitmask) -> barrier -> mask-GEMV
// Select also stores the spike BITMASK (one extra ballot per i — the predicate is
// already wave-resident). GEMV then reads 10 KB of mask words instead of 32 MB of
// float spikes (cross-XCD L3 traffic was the dominant kB cost, R24 diagnostic).
__device__ __forceinline__ unsigned sortkey(float f) {
    unsigned u = __float_as_uint(f);
    return (u & 0x80000000u) ? ~u : (u | 0x80000000u);
}
__device__ __forceinline__ float unsortkey(unsigned u) {
    unsigned ub = (u & 0x80000000u) ? (u ^ 0x80000000u) : ~u;
    return __uint_as_float(ub);
}

__global__ __launch_bounds__(512) void kB_spike_out(
    const float* __restrict__ mem2, const float* __restrict__ Wmlp,
    const float* __restrict__ bmlp, float* __restrict__ spike_out,
    float* __restrict__ out, unsigned* __restrict__ counter,
    unsigned long long* __restrict__ maskws)
{
    __shared__ float wlds[RR];                       // 40 KB: W_mlp row o
    __shared__ float red[8][BB];
    const int tid = threadIdx.x;
    const int blk = blockIdx.x;                      // 100 blocks
    const bool is_sel = (blk < 40) && (tid < 64);    // select wave

    // ---- stage W_mlp[o] into LDS (all non-select threads; overlaps select below)
    if (!is_sel) {
        const int nstage = (blk < 40) ? 448 : 512;
        const int stid   = (blk < 40) ? (tid - 64) : tid;
        for (int j = stid; j < 2500; j += nstage) {
            const int col = j * 4;
            *(float4*)&wlds[col] = *(const float4*)(Wmlp + (size_t)blk * RR + col);
        }
    }

    // ---- phase A: blocks 0..39, wave 0 only — exact order stats + spike + mask
    if (is_sel) {
        const int b = blk / 5, k = blk - b * 5;
        const int lane = tid;
        const float* src = mem2 + (k * BB + b) * NBL;

        float    f[32];
        unsigned u[32];
        #pragma unroll
        for (int i = 0; i < 32; ++i) {
            int nb = i * 64 + lane;
            f[i] = (nb < NBL) ? src[nb] : 0.f;
            u[i] = (nb < NBL) ? sortkey(f[i]) : 0u;  // pad key = smallest
        }

        // rank-159 (160th largest): max X with count(u >= X) >= 160 (ballot+popc)
        unsigned X = 0;
        for (int bit = 31; bit >= 0; --bit) {
            unsigned cand = X | (1u << bit);
            int c = 0;
            #pragma unroll
            for (int i = 0; i < 32; ++i)
                c += (int)__popcll(__ballot(u[i] >= cand));
            if (c >= 160) X = cand;
        }
        const unsigned q2u = X;                      // mem_q2 (rank 159)

        int cge = 0;
        #pragma unroll
        for (int i = 0; i < 32; ++i)
            cge += (int)__popcll(__ballot(u[i] >= q2u));

        unsigned q1u;
        if (cge >= 161) {
            q1u = q2u;                               // ties reach rank 160
        } else {
            unsigned m = 0;
            #pragma unroll
            for (int i = 0; i < 32; ++i)
                if (u[i] < q2u && u[i] > m) m = u[i];
            #pragma unroll
            for (int o = 32; o >= 1; o >>= 1) {
                unsigned ot = __shfl_xor(m, o, 64);
                m = (ot > m) ? ot : m;
            }
            q1u = m;                                 // mem_q1 (rank 160)
        }

        const float q2 = unsortkey(q2u), q1 = unsortkey(q1u);
        const float nps = q1 + (q2 - q1) * 0.2f;

        unsigned long long* maskp = maskws + blk * 32;   // blk == b*5+k
        #pragma unroll
        for (int i = 0; i < 32; ++i) {
            int nb = i * 64 + lane;
            const bool sp = (nb < NBL) && (f[i] - nps > 0.1f);
            const unsigned long long m = __ballot(sp);   // bit l <-> nb = i*64+l
            if (nb < NBL)
                spike_out[b * RR + nb * 5 + k] = sp ? 1.0f : 0.0f;
            if (lane == 0) maskp[i] = m;
        }
        __threadfence();                             // release spike + mask stores
        if (lane == 0) atomicAdd(counter, 1u);       // device-scope by default
    }

    // ---- barrier: all 100 blocks co-resident (<=256 CUs), spin on counter
    __syncthreads();                                 // also fences the LDS staging
    if (tid == 0) {
        while (__hip_atomic_load(counter, __ATOMIC_ACQUIRE, __HIP_MEMORY_SCOPE_AGENT) < 40u)
            __builtin_amdgcn_s_sleep(2);
        __threadfence();                             // belt-and-braces acquire
    }
    __syncthreads();

    // ---- phase B: mask-GEMV. out[b][o] = sum_nb sum_k bit(b,k,nb)*W[o][nb*5+k].
    // 32 nb-chunks of 64 split over 8 waves (4 each); W from LDS (stride-5 = 2-way
    // bank alias, free); mask words are wave-uniform broadcast loads from L2.
    const int o = blk;
    const int wave = tid >> 6, lane = tid & 63;

    float acc[BB];
    #pragma unroll
    for (int b = 0; b < BB; ++b) acc[b] = 0.f;

    for (int c = wave; c < 32; c += 8) {
        const int nb  = c * 64 + lane;
        const int nbc = (nb < NBL) ? nb : (NBL - 1);     // clamp; masked bits are 0
        const float* wp5 = &wlds[nbc * 5];
        #pragma unroll
        for (int k = 0; k < 5; ++k) {
            const float wk = wp5[k];
            #pragma unroll
            for (int b = 0; b < BB; ++b) {
                const unsigned long long m = maskws[(b * 5 + k) * 32 + c];
                acc[b] += (((unsigned)(m >> lane)) & 1u) ? wk : 0.f;
            }
        }
    }

    // intra-wave reduce (zero-DS DPP, total in lane 63) -> cross-wave via LDS
    #pragma unroll
    for (int b = 0; b < BB; ++b) {
        float v = acc[b];
        v = dpp_add<0xB1>(v);
        v = dpp_add<0x4E>(v);
        v = dpp_add<0x141>(v);
        v = dpp_add<0x140>(v);
        v = dpp_add<0x142>(v);
        v = dpp_add<0x143>(v);
        if (lane == 63) red[wave][b] = v;
    }
    __syncthreads();
    if (tid < BB) {
        float v = 0.f;
        #pragma unroll
        for (int w = 0; w < 8; ++w) v += red[w][tid];
        out[tid * 100 + o] = v + bmlp[o];
    }
}

extern "C" void kernel_launch(void* const* d_in, const int* in_sizes, int n_in,
                              void* d_out, int out_size, void* d_ws, size_t ws_size,
                              hipStream_t stream) {
    const float* in1  = (const float*)d_in[0];
    const float* in2  = (const float*)d_in[1];
    const float* in3  = (const float*)d_in[2];
    const float* in4  = (const float*)d_in[3];
    const float* in5  = (const float*)d_in[4];
    const float* Wfc  = (const float*)d_in[5];
    const float* bfc  = (const float*)d_in[6];
    // d_in[7] = W_fv : multiplied by zero spikes — never read (saves 400 MB)
    const float* bfv  = (const float*)d_in[8];
    const float* Wmlp = (const float*)d_in[9];
    const float* bmlp = (const float*)d_in[10];

    float* out   = (float*)d_out;          // 8*100 = 800 floats
    float* spike = out + 800;              // 8*10000 floats (r_sumspike)

    float*    mem2    = (float*)d_ws;      // 80000 floats, layout [q][b][nb]
    unsigned* counter = (unsigned*)((char*)d_ws + 80000 * sizeof(float));
    unsigned long long* maskws =
        (unsigned long long*)((char*)d_ws + 80000 * sizeof(float) + 16); // 8B-aligned

    kA_gemm<<<2000, 256, 0, stream>>>(in1, in2, in3, in4, in5, Wfc, bfc, bfv,
                                      mem2, counter);
    kB_spike_out<<<100, 512, 0, stream>>>(mem2, Wmlp, bmlp, spike, out, counter,
                                          maskws);
}

// Round 26
// 54.069 us; speedup vs baseline: 1.4059x; 1.0668x over previous
//
#include <hip/hip_runtime.h>

#define BB   8
#define NBL  2000
#define RR   10000
#define XDIM 2000

// v += dpp_permuted(v): single VALU op (v_add_f32 with DPP modifier), no DS pipe.
// Full 64-lane sum sequence (standard GCN DPP reduction; result in lane 63).
template <int CTRL>
__device__ __forceinline__ float dpp_add(float v) {
    int s = __builtin_amdgcn_update_dpp(0, __float_as_int(v), CTRL, 0xf, 0xf, true);
    return v + __int_as_float(s);
}

// ---------------- kernel A (champion, byte-identical to R23): mem2[q][b][nb]
__global__ __launch_bounds__(256, 4) void kA_gemm(
    const float* __restrict__ in1, const float* __restrict__ in2,
    const float* __restrict__ in3, const float* __restrict__ in4,
    const float* __restrict__ in5,
    const float* __restrict__ Wfc, const float* __restrict__ bfc,
    const float* __restrict__ bfv, float* __restrict__ mem2,
    unsigned* __restrict__ counter)
{
    // re-arm the kernel-B barrier every call (stream order publishes it before kB)
    if (blockIdx.x == 0 && threadIdx.x == 0) *counter = 0u;

    const int tid  = threadIdx.x;
    const int wave = tid >> 6, lane = tid & 63;     // wave = column quarter 0..3
    const int nb    = blockIdx.x;                   // 0..1999
    const int rbase = nb * 5;

    float acc[5][BB];
    #pragma unroll
    for (int q = 0; q < 5; ++q)
        #pragma unroll
        for (int b = 0; b < BB; ++b) acc[q][b] = 0.f;

    #pragma unroll
    for (int i = 0; i < 2; ++i) {
        const int col = wave * 512 + i * 256 + (lane << 2);   // float4-aligned
        const bool valid = col < XDIM;              // tail: wave==3,i==1, lanes>=52
        const int wh  = col / 400;                  // concat segment (5 only if invalid)
        const int off = col - wh * 400;             // f4 never crosses a 400-boundary
        const float* xp = in1;
        xp = (wh == 1) ? in2 : xp;
        xp = (wh == 2) ? in3 : xp;
        xp = (wh == 3) ? in4 : xp;
        xp = (wh == 4) ? in5 : xp;

        float4 w[5];
        #pragma unroll
        for (int q = 0; q < 5; ++q)
            w[q] = valid ? *(const float4*)(Wfc + (size_t)(rbase + q) * XDIM + col)
                         : make_float4(0.f, 0.f, 0.f, 0.f);

        #pragma unroll
        for (int b = 0; b < BB; ++b) {
            float4 xv = valid ? *(const float4*)(xp + b * 400 + off)
                              : make_float4(0.f, 0.f, 0.f, 0.f);
            #pragma unroll
            for (int q = 0; q < 5; ++q)
                acc[q][b] += w[q].x * xv.x + w[q].y * xv.y + w[q].z * xv.z + w[q].w * xv.w;
        }
    }

    // intra-wave reduce: 6 DPP adds, all VALU pipe; total lands in lane 63
    __shared__ float part[4][5][BB];                // [wave][q][b], 640 B
    #pragma unroll
    for (int q = 0; q < 5; ++q) {
        #pragma unroll
        for (int b = 0; b < BB; ++b) {
            float v = acc[q][b];
            v = dpp_add<0xB1>(v);                   // quad xor1
            v = dpp_add<0x4E>(v);                   // quad xor2
            v = dpp_add<0x141>(v);                  // row_half_mirror
            v = dpp_add<0x140>(v);                  // row_mirror -> row sums
            v = dpp_add<0x142>(v);                  // row_bcast15
            v = dpp_add<0x143>(v);                  // row_bcast31 -> lane 63 total
            if (lane == 63) part[wave][q][b] = v;
        }
    }
    __syncthreads();

    if (wave == 0 && lane < 40) {                   // 40 outputs: q = lane>>3, b = lane&7
        const int q = lane >> 3, b = lane & 7;
        const int r = rbase + q;
        const float v = part[0][q][b] + part[1][q][b] + part[2][q][b] + part[3][q][b];
        mem2[(q * BB + b) * NBL + nb] = v + bfc[r] + bfv[r] + 0.05f;
    }
}

// ---------------- kernel B v3: select -> publish nps -> barrier -> {parallel spike
// write + GEMV with on-the-fly spike recompute from mem2 (clean L3) + npslds}.
// Removes (a) the 2000 scattered spike stores from the barrier critical path and
// (b) the GEMV's 32 MB read of dirty cross-XCD spike lines (R24/R25 diagnosis).
__device__ __forceinline__ unsigned sortkey(float f) {
    unsigned u = __float_as_uint(f);
    return (u & 0x80000000u) ? ~u : (u | 0x80000000u);
}
__device__ __forceinline__ float unsortkey(unsigned u) {
    unsigned ub = (u & 0x80000000u) ? (u ^ 0x80000000u) : ~u;
    return __uint_as_float(ub);
}

__global__ __launch_bounds__(512) void kB_spike_out(
    const float* __restrict__ mem2, const float* __restrict__ Wmlp,
    const float* __restrict__ bmlp, float* __restrict__ spike_out,
    float* __restrict__ out, unsigned* __restrict__ counter,
    float* __restrict__ npsws)
{
    __shared__ float wlds[RR];                       // 40 KB: W_mlp row o
    __shared__ float red[8][BB];
    __shared__ float npslds[40];
    const int tid = threadIdx.x;
    const int blk = blockIdx.x;                      // 100 blocks
    const bool is_sel = (blk < 40) && (tid < 64);    // select wave

    // ---- stage W_mlp[o] into LDS (all non-select threads; overlaps select below)
    if (!is_sel) {
        const int nstage = (blk < 40) ? 448 : 512;
        const int stid   = (blk < 40) ? (tid - 64) : tid;
        for (int j = stid; j < 2500; j += nstage) {
            const int col = j * 4;
            *(float4*)&wlds[col] = *(const float4*)(Wmlp + (size_t)blk * RR + col);
        }
    }

    // ---- phase A: blocks 0..39, wave 0 only — exact order stats -> publish nps
    if (is_sel) {
        const int b = blk / 5, k = blk - b * 5;
        const int lane = tid;
        const float* src = mem2 + (k * BB + b) * NBL;

        float    f[32];
        unsigned u[32];
        #pragma unroll
        for (int i = 0; i < 32; ++i) {
            int nb = i * 64 + lane;
            f[i] = (nb < NBL) ? src[nb] : 0.f;
            u[i] = (nb < NBL) ? sortkey(f[i]) : 0u;  // pad key = smallest
        }

        // rank-159 (160th largest): max X with count(u >= X) >= 160 (ballot+popc)
        unsigned X = 0;
        for (int bit = 31; bit >= 0; --bit) {
            unsigned cand = X | (1u << bit);
            int c = 0;
            #pragma unroll
            for (int i = 0; i < 32; ++i)
                c += (int)__popcll(__ballot(u[i] >= cand));
            if (c >= 160) X = cand;
        }
        const unsigned q2u = X;                      // mem_q2 (rank 159)

        int cge = 0;
        #pragma unroll
        for (int i = 0; i < 32; ++i)
            cge += (int)__popcll(__ballot(u[i] >= q2u));

        unsigned q1u;
        if (cge >= 161) {
            q1u = q2u;                               // ties reach rank 160
        } else {
            unsigned m = 0;
            #pragma unroll
            for (int i = 0; i < 32; ++i)
                if (u[i] < q2u && u[i] > m) m = u[i];
            #pragma unroll
            for (int o = 32; o >= 1; o >>= 1) {
                unsigned ot = __shfl_xor(m, o, 64);
                m = (ot > m) ? ot : m;
            }
            q1u = m;                                 // mem_q1 (rank 160)
        }

        const float q2 = unsortkey(q2u), q1 = unsortkey(q1u);
        const float nps = q1 + (q2 - q1) * 0.2f;

        if (lane == 0) npsws[blk] = nps;             // publish ONLY nps (40 floats)
        __threadfence();                             // release
        if (lane == 0) atomicAdd(counter, 1u);       // device-scope by default
    }

    // ---- barrier: all 100 blocks co-resident (<=256 CUs), spin on counter
    __syncthreads();                                 // also fences the LDS staging
    if (tid == 0) {
        while (__hip_atomic_load(counter, __ATOMIC_ACQUIRE, __HIP_MEMORY_SCOPE_AGENT) < 40u)
            __builtin_amdgcn_s_sleep(2);
        __threadfence();                             // acquire
    }
    __syncthreads();

    // ---- broadcast nps to LDS (all blocks)
    if (tid < 40) npslds[tid] = npsws[tid];
    __syncthreads();

    // ---- spike write (blocks 0..39, ALL 512 threads — off everyone's critical path)
    if (blk < 40) {
        const int b = blk / 5, k = blk - b * 5;
        const float nps = npslds[blk];
        if (tid < 500) {                             // 500 f4 = 2000 values
            const float4 v = *(const float4*)(mem2 + (k * BB + b) * NBL + tid * 4);
            float* dst = spike_out + b * RR + (tid * 4) * 5 + k;
            dst[0]  = (v.x - nps > 0.1f) ? 1.0f : 0.0f;
            dst[5]  = (v.y - nps > 0.1f) ? 1.0f : 0.0f;
            dst[10] = (v.z - nps > 0.1f) ? 1.0f : 0.0f;
            dst[15] = (v.w - nps > 0.1f) ? 1.0f : 0.0f;
        }
    }

    // ---- phase B: GEMV, spike recomputed on the fly (bitwise-identical predicate).
    // Thread owns nb0 = tid*4 (single pass, 500 active threads/block).
    const int o = blk;
    const int wave = tid >> 6, lane = tid & 63;

    float acc[BB];
    #pragma unroll
    for (int b = 0; b < BB; ++b) acc[b] = 0.f;

    if (tid < 500) {
        const int nb0 = tid * 4;
        float wk[20];                                // W[o][(nb0+j)*5+k], idx = j*5+k
        #pragma unroll
        for (int t = 0; t < 5; ++t)
            *(float4*)&wk[t * 4] = *(const float4*)&wlds[nb0 * 5 + t * 4];

        #pragma unroll
        for (int k = 0; k < 5; ++k) {
            #pragma unroll
            for (int b = 0; b < BB; ++b) {
                const float4 v = *(const float4*)(mem2 + (k * BB + b) * NBL + nb0);
                const float nps = npslds[b * 5 + k];
                acc[b] += (v.x - nps > 0.1f) ? wk[0 * 5 + k] : 0.f;
                acc[b] += (v.y - nps > 0.1f) ? wk[1 * 5 + k] : 0.f;
                acc[b] += (v.z - nps > 0.1f) ? wk[2 * 5 + k] : 0.f;
                acc[b] += (v.w - nps > 0.1f) ? wk[3 * 5 + k] : 0.f;
            }
        }
    }

    // intra-wave reduce (zero-DS DPP, total in lane 63) -> cross-wave via LDS
    #pragma unroll
    for (int b = 0; b < BB; ++b) {
        float v = acc[b];
        v = dpp_add<0xB1>(v);
        v = dpp_add<0x4E>(v);
        v = dpp_add<0x141>(v);
        v = dpp_add<0x140>(v);
        v = dpp_add<0x142>(v);
        v = dpp_add<0x143>(v);
        if (lane == 63) red[wave][b] = v;
    }
    __syncthreads();
    if (tid < BB) {
        float v = 0.f;
        #pragma unroll
        for (int w = 0; w < 8; ++w) v += red[w][tid];
        out[tid * 100 + o] = v + bmlp[o];
    }
}

extern "C" void kernel_launch(void* const* d_in, const int* in_sizes, int n_in,
                              void* d_out, int out_size, void* d_ws, size_t ws_size,
                              hipStream_t stream) {
    const float* in1  = (const float*)d_in[0];
    const float* in2  = (const float*)d_in[1];
    const float* in3  = (const float*)d_in[2];
    const float* in4  = (const float*)d_in[3];
    const float* in5  = (const float*)d_in[4];
    const float* Wfc  = (const float*)d_in[5];
    const float* bfc  = (const float*)d_in[6];
    // d_in[7] = W_fv : multiplied by zero spikes — never read (saves 400 MB)
    const float* bfv  = (const float*)d_in[8];
    const float* Wmlp = (const float*)d_in[9];
    const float* bmlp = (const float*)d_in[10];

    float* out   = (float*)d_out;          // 8*100 = 800 floats
    float* spike = out + 800;              // 8*10000 floats (r_sumspike)

    float*    mem2    = (float*)d_ws;      // 80000 floats, layout [q][b][nb]
    unsigned* counter = (unsigned*)((char*)d_ws + 80000 * sizeof(float));
    float*    npsws   = (float*)((char*)d_ws + 80000 * sizeof(float) + 16);

    kA_gemm<<<2000, 256, 0, stream>>>(in1, in2, in3, in4, in5, Wfc, bfc, bfv,
                                      mem2, counter);
    kB_spike_out<<<100, 512, 0, stream>>>(mem2, Wmlp, bmlp, spike, out, counter,
                                          npsws);
}

// Round 27
// 50.967 us; speedup vs baseline: 1.4915x; 1.0609x over previous
//
#include <hip/hip_runtime.h>

#define BB   8
#define NBL  2000
#define RR   10000
#define XDIM 2000

// v += dpp_permuted(v): single VALU op (v_add_f32 with DPP modifier), no DS pipe.
// Full 64-lane sum sequence (standard GCN DPP reduction; result in lane 63):
//   0xB1 quad_perm[1,0,3,2] | 0x4E quad_perm[2,3,0,1] | 0x141 row_half_mirror |
//   0x140 row_mirror | 0x142 row_bcast15 | 0x143 row_bcast31
template <int CTRL>
__device__ __forceinline__ float dpp_add(float v) {
    int s = __builtin_amdgcn_update_dpp(0, __float_as_int(v), CTRL, 0xf, 0xf, true);
    return v + __int_as_float(s);
}

// ---------------- kernel A (CHAMPION, R23): mem2[q][b][nb] = x·W_fc[nb*5+q] + biases
// 2000 blocks × 256 thr, 4 waves = column quarters; zero-DS DPP reduce.
__global__ __launch_bounds__(256, 4) void kA_gemm(
    const float* __restrict__ in1, const float* __restrict__ in2,
    const float* __restrict__ in3, const float* __restrict__ in4,
    const float* __restrict__ in5,
    const float* __restrict__ Wfc, const float* __restrict__ bfc,
    const float* __restrict__ bfv, float* __restrict__ mem2,
    unsigned* __restrict__ counter)
{
    // re-arm the kernel-B barrier every call (stream order publishes it before kB)
    if (blockIdx.x == 0 && threadIdx.x == 0) *counter = 0u;

    const int tid  = threadIdx.x;
    const int wave = tid >> 6, lane = tid & 63;     // wave = column quarter 0..3
    const int nb    = blockIdx.x;                   // 0..1999
    const int rbase = nb * 5;

    float acc[5][BB];
    #pragma unroll
    for (int q = 0; q < 5; ++q)
        #pragma unroll
        for (int b = 0; b < BB; ++b) acc[q][b] = 0.f;

    #pragma unroll
    for (int i = 0; i < 2; ++i) {
        const int col = wave * 512 + i * 256 + (lane << 2);   // float4-aligned
        const bool valid = col < XDIM;              // tail: wave==3,i==1, lanes>=52
        const int wh  = col / 400;                  // concat segment (5 only if invalid)
        const int off = col - wh * 400;             // f4 never crosses a 400-boundary
        const float* xp = in1;
        xp = (wh == 1) ? in2 : xp;
        xp = (wh == 2) ? in3 : xp;
        xp = (wh == 3) ? in4 : xp;
        xp = (wh == 4) ? in5 : xp;

        float4 w[5];
        #pragma unroll
        for (int q = 0; q < 5; ++q)
            w[q] = valid ? *(const float4*)(Wfc + (size_t)(rbase + q) * XDIM + col)
                         : make_float4(0.f, 0.f, 0.f, 0.f);

        #pragma unroll
        for (int b = 0; b < BB; ++b) {
            float4 xv = valid ? *(const float4*)(xp + b * 400 + off)
                              : make_float4(0.f, 0.f, 0.f, 0.f);
            #pragma unroll
            for (int q = 0; q < 5; ++q)
                acc[q][b] += w[q].x * xv.x + w[q].y * xv.y + w[q].z * xv.z + w[q].w * xv.w;
        }
    }

    // intra-wave reduce: 6 DPP adds, all VALU pipe; total lands in lane 63
    __shared__ float part[4][5][BB];                // [wave][q][b], 640 B
    #pragma unroll
    for (int q = 0; q < 5; ++q) {
        #pragma unroll
        for (int b = 0; b < BB; ++b) {
            float v = acc[q][b];
            v = dpp_add<0xB1>(v);                   // quad xor1
            v = dpp_add<0x4E>(v);                   // quad xor2
            v = dpp_add<0x141>(v);                  // row_half_mirror
            v = dpp_add<0x140>(v);                  // row_mirror -> row sums
            v = dpp_add<0x142>(v);                  // row_bcast15
            v = dpp_add<0x143>(v);                  // row_bcast31 -> lane 63 total
            if (lane == 63) part[wave][q][b] = v;
        }
    }
    __syncthreads();

    if (wave == 0 && lane < 40) {                   // 40 outputs: q = lane>>3, b = lane&7
        const int q = lane >> 3, b = lane & 7;
        const int r = rbase + q;
        const float v = part[0][q][b] + part[1][q][b] + part[2][q][b] + part[3][q][b];
        mem2[(q * BB + b) * NBL + nb] = v + bfc[r] + bfv[r] + 0.05f;
    }
}

// ---------------- kernel B (CHAMPION, R15/R23): select+spike -> barrier -> GEMV
// with W_mlp LDS-staged by non-select waves during the spin window.
__device__ __forceinline__ unsigned sortkey(float f) {
    unsigned u = __float_as_uint(f);
    return (u & 0x80000000u) ? ~u : (u | 0x80000000u);
}
__device__ __forceinline__ float unsortkey(unsigned u) {
    unsigned ub = (u & 0x80000000u) ? (u ^ 0x80000000u) : ~u;
    return __uint_as_float(ub);
}

__global__ __launch_bounds__(512) void kB_spike_out(
    const float* __restrict__ mem2, const float* __restrict__ Wmlp,
    const float* __restrict__ bmlp, float* __restrict__ spike_out,
    float* __restrict__ out, unsigned* __restrict__ counter)
{
    __shared__ float wlds[RR];                       // 40 KB: W_mlp row o
    const int tid = threadIdx.x;
    const int blk = blockIdx.x;                      // 100 blocks
    const bool is_sel = (blk < 40) && (tid < 64);    // select wave

    // ---- stage W_mlp[o] into LDS (all non-select threads; overlaps select below)
    if (!is_sel) {
        const int nstage = (blk < 40) ? 448 : 512;
        const int stid   = (blk < 40) ? (tid - 64) : tid;
        for (int j = stid; j < 2500; j += nstage) {
            const int col = j * 4;
            *(float4*)&wlds[col] = *(const float4*)(Wmlp + (size_t)blk * RR + col);
        }
    }

    // ---- phase A: blocks 0..39, wave 0 only — exact order stats + spike write
    if (is_sel) {
        const int b = blk / 5, k = blk - b * 5;
        const int lane = tid;
        const float* src = mem2 + (k * BB + b) * NBL;

        float    f[32];
        unsigned u[32];
        #pragma unroll
        for (int i = 0; i < 32; ++i) {
            int nb = i * 64 + lane;
            f[i] = (nb < NBL) ? src[nb] : 0.f;
            u[i] = (nb < NBL) ? sortkey(f[i]) : 0u;  // pad key = smallest
        }

        // rank-159 (160th largest): max X with count(u >= X) >= 160 (ballot+popc)
        unsigned X = 0;
        for (int bit = 31; bit >= 0; --bit) {
            unsigned cand = X | (1u << bit);
            int c = 0;
            #pragma unroll
            for (int i = 0; i < 32; ++i)
                c += (int)__popcll(__ballot(u[i] >= cand));
            if (c >= 160) X = cand;
        }
        const unsigned q2u = X;                      // mem_q2 (rank 159)

        int cge = 0;
        #pragma unroll
        for (int i = 0; i < 32; ++i)
            cge += (int)__popcll(__ballot(u[i] >= q2u));

        unsigned q1u;
        if (cge >= 161) {
            q1u = q2u;                               // ties reach rank 160
        } else {
            unsigned m = 0;
            #pragma unroll
            for (int i = 0; i < 32; ++i)
                if (u[i] < q2u && u[i] > m) m = u[i];
            #pragma unroll
            for (int o = 32; o >= 1; o >>= 1) {
                unsigned ot = __shfl_xor(m, o, 64);
                m = (ot > m) ? ot : m;
            }
            q1u = m;                                 // mem_q1 (rank 160)
        }

        const float q2 = unsortkey(q2u), q1 = unsortkey(q1u);
        const float nps = q1 + (q2 - q1) * 0.2f;

        #pragma unroll
        for (int i = 0; i < 32; ++i) {
            int nb = i * 64 + lane;
            if (nb < NBL)
                spike_out[b * RR + nb * 5 + k] = (f[i] - nps > 0.1f) ? 1.0f : 0.0f;
        }
        __threadfence();                             // release spike stores
        if (lane == 0) atomicAdd(counter, 1u);       // device-scope by default
    }

    // ---- barrier: all 100 blocks co-resident (<=256 CUs), spin on counter
    __syncthreads();                                 // also fences the LDS staging
    if (tid == 0) {
        while (__hip_atomic_load(counter, __ATOMIC_ACQUIRE, __HIP_MEMORY_SCOPE_AGENT) < 40u)
            __builtin_amdgcn_s_sleep(2);
        __threadfence();                             // belt-and-braces acquire
    }
    __syncthreads();

    // ---- phase B: block = output column o; out[b][o] = spike[b]·W_mlp[o] + b_mlp[o]
    const int o = blk;
    const int wave = tid >> 6, lane = tid & 63;

    float acc[BB];
    #pragma unroll
    for (int b = 0; b < BB; ++b) acc[b] = 0.f;

    #pragma unroll
    for (int i = 0; i < 5; ++i) {
        int col = i * 2048 + tid * 4;                // 512 thr × f4 = 2048 floats/iter
        if (col < RR) {                              // last valid f4 at 9996
            float4 w = *(const float4*)&wlds[col];
            #pragma unroll
            for (int b = 0; b < BB; ++b) {
                float4 s = *(const float4*)(spike_out + b * RR + col);
                acc[b] += w.x * s.x + w.y * s.y + w.z * s.z + w.w * s.w;
            }
        }
    }

    __shared__ float red[8][BB];
    #pragma unroll
    for (int b = 0; b < BB; ++b) {
        float v = acc[b];
        #pragma unroll
        for (int off = 32; off >= 1; off >>= 1) v += __shfl_xor(v, off, 64);
        if (lane == 0) red[wave][b] = v;
    }
    __syncthreads();
    if (tid < BB) {
        float v = 0.f;
        #pragma unroll
        for (int w = 0; w < 8; ++w) v += red[w][tid];
        out[tid * 100 + o] = v + bmlp[o];
    }
}

extern "C" void kernel_launch(void* const* d_in, const int* in_sizes, int n_in,
                              void* d_out, int out_size, void* d_ws, size_t ws_size,
                              hipStream_t stream) {
    const float* in1  = (const float*)d_in[0];
    const float* in2  = (const float*)d_in[1];
    const float* in3  = (const float*)d_in[2];
    const float* in4  = (const float*)d_in[3];
    const float* in5  = (const float*)d_in[4];
    const float* Wfc  = (const float*)d_in[5];
    const float* bfc  = (const float*)d_in[6];
    // d_in[7] = W_fv : multiplied by zero spikes — never read (saves 400 MB)
    const float* bfv  = (const float*)d_in[8];
    const float* Wmlp = (const float*)d_in[9];
    const float* bmlp = (const float*)d_in[10];

    float* out   = (float*)d_out;          // 8*100 = 800 floats
    float* spike = out + 800;              // 8*10000 floats (r_sumspike)

    float*    mem2    = (float*)d_ws;      // 80000 floats, layout [q][b][nb]
    unsigned* counter = (unsigned*)((char*)d_ws + 80000 * sizeof(float));

    kA_gemm<<<2000, 256, 0, stream>>>(in1, in2, in3, in4, in5, Wfc, bfc, bfv,
                                      mem2, counter);
    kB_spike_out<<<100, 512, 0, stream>>>(mem2, Wmlp, bmlp, spike, out, counter);
}